// Round 4
// baseline (404.427 us; speedup 1.0000x reference)
//
#include <hip/hip_runtime.h>

// LSTM: HIDDEN=128, SEQ=7, BATCH=65536. fp32 in/out.
// Split-fp16 2-pass MFMA GEMM per timestep (Ahi*Bhi + Alo*Bhi), c state in
// registers, h staged via LDS.
//
// R2: __launch_bounds__(256,1) — (256,2) spilled ~1.4GB/dispatch. 544->297us.
// R3: dropped W_lo pass (absmax unchanged 2.44e-4 -> split not the error
//     source). 297->252us. Diagnosis: 280 total regs -> 1 wave/SIMD,
//     latency-bound (3x stall factor vs pipe model).
// R4: BT=32 (2048 blocks) + launch_bounds(256,3) -> target 3 waves/SIMD;
//     double-buffered h/xs/predp in LDS -> ONE barrier per timestep (was 3).

#define SEQ 7
#define BT 32

typedef _Float16 half8 __attribute__((ext_vector_type(8)));
typedef float floatx4 __attribute__((ext_vector_type(4)));

__device__ __forceinline__ floatx4 mfma16(half8 a, half8 b, floatx4 c) {
  return __builtin_amdgcn_mfma_f32_16x16x32_f16(a, b, c, 0, 0, 0);
}

__device__ __forceinline__ float fsig(float v) {
  float e = __expf(-v);
  return __builtin_amdgcn_rcpf(1.0f + e);
}
__device__ __forceinline__ float ftanh(float v) {
  float e = __expf(-2.0f * v);
  return 2.0f * __builtin_amdgcn_rcpf(1.0f + e) - 1.0f;
}

// Pack W_hh [512][128] fp32 into fragment-major fp16 (hi part only).
// B-operand layout for mfma_f32_16x16x32_f16: lane = kq*16 + col holds
// B[k = kq*8 + jj][n = col] for the 16-col tile.
__global__ void pack_kernel(const float* __restrict__ Whh,
                            _Float16* __restrict__ Bp) {
  int idx = blockIdx.x * 256 + threadIdx.x;   // 0..65535 = j*128 + k
  float wv = Whh[idx];
  _Float16 hi = (_Float16)wv;
  int j = idx >> 7, k = idx & 127;
  int nt = j >> 4, col = j & 15;              // 16-col N-tile, col within
  int kk = k >> 5, r = k & 31;                // 32-K step, k within
  int kq = r >> 3, jj = r & 7;
  int base = (((nt << 2) + kk) * 64 + (kq << 4) + col) * 8 + jj;
  Bp[base] = hi;
}

__launch_bounds__(256, 3)
__global__ void lstm_kernel(const float* __restrict__ x,
                            const float* __restrict__ x0,
                            const float* __restrict__ Wih,
                            const float* __restrict__ bih,
                            const float* __restrict__ bhh,
                            const float* __restrict__ Wout,
                            const float* __restrict__ boutp,
                            const _Float16* __restrict__ Bp,
                            float* __restrict__ out) {
  // h staged as fp16 hi/lo, double-buffered: [buf][row][k] with +8 pad
  // (272B stride -> conflict-free ds_read_b128 A-fragments, 16B aligned).
  __shared__ _Float16 Ahi[2][BT][136];
  __shared__ _Float16 Alo[2][BT][136];
  __shared__ float xs[2][BT];
  __shared__ float predp[2][4][BT];

  const int tid = threadIdx.x;
  const int w = tid >> 6;          // wave 0..3: owns hc [32w, 32w+32)
  const int lane = tid & 63;
  const int col = lane & 15;
  const int quad = lane >> 4;
  const int rowbase = blockIdx.x * BT;

  // zero h state buf0 (h0 = 0)
  {
    unsigned int* a0 = (unsigned int*)&Ahi[0][0][0];
    unsigned int* a1 = (unsigned int*)&Alo[0][0][0];
    for (int i = tid; i < BT * 136 / 2; i += 256) { a0[i] = 0u; a1[i] = 0u; }
  }
  if (tid < BT) xs[0][tid] = x0[rowbase + tid];  // input for t=0

  // per-lane constants: gate col j = g*128 + w*32 + s*16 + col
  float wih_r[4][2], bias_r[4][2];
#pragma unroll
  for (int g = 0; g < 4; ++g)
#pragma unroll
    for (int s = 0; s < 2; ++s) {
      int j = g * 128 + w * 32 + s * 16 + col;
      wih_r[g][s] = Wih[j];
      bias_r[g][s] = bih[j] + bhh[j];
    }
  float wout_r[2];
  wout_r[0] = Wout[w * 32 + col];
  wout_r[1] = Wout[w * 32 + 16 + col];
  const float bout = boutp[0];

  float c_r[2][2][4];  // [mt][s][reg] cell state, fp32, in registers
#pragma unroll
  for (int mt = 0; mt < 2; ++mt)
#pragma unroll
    for (int s = 0; s < 2; ++s)
#pragma unroll
      for (int r = 0; r < 4; ++r) c_r[mt][s][r] = 0.f;

  float hn0[2][4];  // s=0 h_new held until s=1 pairs it for staging
  float pp[2][4];   // pred partial

  __syncthreads();  // prologue: buf0 + xs[0] ready

#pragma unroll 1
  for (int t = 0; t < SEQ; ++t) {
    const int cur = t & 1, nxt = cur ^ 1;

    // drain pred of t-1 (predp[(t-1)&1] == predp[nxt] complete as of last
    // barrier; this iteration's epilogue writes predp[cur], no clash)
    if (t > 0 && tid < BT) {
      float p = predp[nxt][0][tid] + predp[nxt][1][tid] +
                predp[nxt][2][tid] + predp[nxt][3][tid] + bout;
      out[(size_t)(rowbase + tid) * 7 + (t - 1)] = p;
    }
    // prefetch input for t+1 into the other xs buffer (consumed after the
    // end-of-body barrier; old contents were last read before prev barrier)
    if (t + 1 < SEQ && tid < BT) {
      xs[nxt][tid] = x[(size_t)(rowbase + tid) * 7 + t];
    }

#pragma unroll
    for (int s = 0; s < 2; ++s) {
      floatx4 acc[2][4];  // [mt][g]
#pragma unroll
      for (int mt = 0; mt < 2; ++mt)
#pragma unroll
        for (int g = 0; g < 4; ++g)
          acc[mt][g] = (floatx4){0.f, 0.f, 0.f, 0.f};

#pragma unroll
      for (int kk = 0; kk < 4; ++kk) {
        half8 ahi[2], alo[2];
        const int k0 = kk * 32 + quad * 8;
#pragma unroll
        for (int mt = 0; mt < 2; ++mt) {
          const int row = mt * 16 + col;  // A: m = lane&15 within tile
          ahi[mt] = *(const half8*)&Ahi[cur][row][k0];
          alo[mt] = *(const half8*)&Alo[cur][row][k0];
        }
#pragma unroll
        for (int g = 0; g < 4; ++g) {
          const int nt = g * 8 + w * 2 + s;
          const int off = ((nt * 4 + kk) * 64 + lane) * 8;
          half8 bhi = *(const half8*)(Bp + off);
#pragma unroll
          for (int mt = 0; mt < 2; ++mt) {
            acc[mt][g] = mfma16(ahi[mt], bhi, acc[mt][g]);  // hi*hi
            acc[mt][g] = mfma16(alo[mt], bhi, acc[mt][g]);  // lo*hi
          }
        }
      }

#pragma unroll
      for (int mt = 0; mt < 2; ++mt) {
#pragma unroll
        for (int r = 0; r < 4; ++r) {
          const int b_loc = mt * 16 + quad * 4 + r;  // C row
          const float xv = xs[cur][b_loc];
          float G0 = acc[mt][0][r] + (xv * wih_r[0][s] + bias_r[0][s]);
          float G1 = acc[mt][1][r] + (xv * wih_r[1][s] + bias_r[1][s]);
          float G2 = acc[mt][2][r] + (xv * wih_r[2][s] + bias_r[2][s]);
          float G3 = acc[mt][3][r] + (xv * wih_r[3][s] + bias_r[3][s]);
          float ig = fsig(G0);
          float fg = fsig(G1);
          float gg = ftanh(G2);
          float og = fsig(G3);
          float cn = fg * c_r[mt][s][r] + ig * gg;
          c_r[mt][s][r] = cn;
          float hn = og * ftanh(cn);
          if (s == 0) {
            hn0[mt][r] = hn;
            pp[mt][r] = hn * wout_r[0];
          } else {
            pp[mt][r] += hn * wout_r[1];
            // stage h_new (hi/lo fp16) into the NEXT buffer
            float h0 = hn0[mt][r];
            _Float16 h0h = (_Float16)h0;
            _Float16 h0l = (_Float16)(h0 - (float)h0h);
            _Float16 h1h = (_Float16)hn;
            _Float16 h1l = (_Float16)(hn - (float)h1h);
            const int hc0 = w * 32 + col;
            Ahi[nxt][b_loc][hc0] = h0h;
            Alo[nxt][b_loc][hc0] = h0l;
            Ahi[nxt][b_loc][hc0 + 16] = h1h;
            Alo[nxt][b_loc][hc0 + 16] = h1l;
            // reduce pred over the 16 cols this wave holds for this row
            float v = pp[mt][r];
            v += __shfl_xor(v, 1, 64);
            v += __shfl_xor(v, 2, 64);
            v += __shfl_xor(v, 4, 64);
            v += __shfl_xor(v, 8, 64);
            if (col == 0) predp[cur][w][b_loc] = v;
          }
        }
      }
    }
    __syncthreads();  // single barrier: staging, predp, xs prefetch complete
  }

  // drain pred of t=6 (predp[(SEQ-1)&1] = predp[0])
  if (tid < BT) {
    float p = predp[0][0][tid] + predp[0][1][tid] +
              predp[0][2][tid] + predp[0][3][tid] + bout;
    out[(size_t)(rowbase + tid) * 7 + (SEQ - 1)] = p;
  }
}

extern "C" void kernel_launch(void* const* d_in, const int* in_sizes, int n_in,
                              void* d_out, int out_size, void* d_ws, size_t ws_size,
                              hipStream_t stream) {
  const float* x    = (const float*)d_in[0];
  const float* x0   = (const float*)d_in[1];
  const float* Wih  = (const float*)d_in[2];
  const float* Whh  = (const float*)d_in[3];
  const float* bih  = (const float*)d_in[4];
  const float* bhh  = (const float*)d_in[5];
  const float* Wout = (const float*)d_in[6];
  const float* bout = (const float*)d_in[7];
  float* out = (float*)d_out;
  _Float16* Bp = (_Float16*)d_ws;  // 128 KB fragment-major W_hh (fp16 hi)

  pack_kernel<<<256, 256, 0, stream>>>(Whh, Bp);
  lstm_kernel<<<65536 / BT, 256, 0, stream>>>(x, x0, Wih, bih, bhh, Wout, bout,
                                              Bp, out);
}

// Round 5
// 237.890 us; speedup vs baseline: 1.7001x; 1.7001x over previous
//
#include <hip/hip_runtime.h>

// LSTM: HIDDEN=128, SEQ=7, BATCH=65536. fp32 in/out.
// Split-fp16 2-pass MFMA GEMM per timestep (Ahi*Bhi + Alo*Bhi), c state in
// registers, h staged via LDS.
//
// R2: launch_bounds(256,1) — (256,2)@BT=64 spilled ~1.4GB. 544->297us.
// R3: dropped W_lo pass (absmax unchanged). 297->252us. 1 wave/SIMD.
// R4: BT=32 + dbuf LDS + 1 barrier/t. Structure OK but (256,3) made the
//     allocator pick 84 VGPRs -> 1.25GB spills, 368us. REGRESSION.
// R5: same structure, launch_bounds(256,2): cap 256 regs, demand ~170 ->
//     spill-free, 2 waves/SIMD, 2 blocks/CU.

#define SEQ 7
#define BT 32

typedef _Float16 half8 __attribute__((ext_vector_type(8)));
typedef float floatx4 __attribute__((ext_vector_type(4)));

__device__ __forceinline__ floatx4 mfma16(half8 a, half8 b, floatx4 c) {
  return __builtin_amdgcn_mfma_f32_16x16x32_f16(a, b, c, 0, 0, 0);
}

__device__ __forceinline__ float fsig(float v) {
  float e = __expf(-v);
  return __builtin_amdgcn_rcpf(1.0f + e);
}
__device__ __forceinline__ float ftanh(float v) {
  float e = __expf(-2.0f * v);
  return 2.0f * __builtin_amdgcn_rcpf(1.0f + e) - 1.0f;
}

// Pack W_hh [512][128] fp32 into fragment-major fp16 (hi part only).
// B-operand layout for mfma_f32_16x16x32_f16: lane = kq*16 + col holds
// B[k = kq*8 + jj][n = col] for the 16-col tile.
__global__ void pack_kernel(const float* __restrict__ Whh,
                            _Float16* __restrict__ Bp) {
  int idx = blockIdx.x * 256 + threadIdx.x;   // 0..65535 = j*128 + k
  float wv = Whh[idx];
  _Float16 hi = (_Float16)wv;
  int j = idx >> 7, k = idx & 127;
  int nt = j >> 4, col = j & 15;              // 16-col N-tile, col within
  int kk = k >> 5, r = k & 31;                // 32-K step, k within
  int kq = r >> 3, jj = r & 7;
  int base = (((nt << 2) + kk) * 64 + (kq << 4) + col) * 8 + jj;
  Bp[base] = hi;
}

__launch_bounds__(256, 2)
__global__ void lstm_kernel(const float* __restrict__ x,
                            const float* __restrict__ x0,
                            const float* __restrict__ Wih,
                            const float* __restrict__ bih,
                            const float* __restrict__ bhh,
                            const float* __restrict__ Wout,
                            const float* __restrict__ boutp,
                            const _Float16* __restrict__ Bp,
                            float* __restrict__ out) {
  // h staged as fp16 hi/lo, double-buffered: [buf][row][k] with +8 pad
  // (272B stride -> conflict-free ds_read_b128 A-fragments, 16B aligned).
  __shared__ _Float16 Ahi[2][BT][136];
  __shared__ _Float16 Alo[2][BT][136];
  __shared__ float xs[2][BT];
  __shared__ float predp[2][4][BT];

  const int tid = threadIdx.x;
  const int w = tid >> 6;          // wave 0..3: owns hc [32w, 32w+32)
  const int lane = tid & 63;
  const int col = lane & 15;
  const int quad = lane >> 4;
  const int rowbase = blockIdx.x * BT;

  // zero h state buf0 (h0 = 0)
  {
    unsigned int* a0 = (unsigned int*)&Ahi[0][0][0];
    unsigned int* a1 = (unsigned int*)&Alo[0][0][0];
    for (int i = tid; i < BT * 136 / 2; i += 256) { a0[i] = 0u; a1[i] = 0u; }
  }
  if (tid < BT) xs[0][tid] = x0[rowbase + tid];  // input for t=0

  // per-lane constants: gate col j = g*128 + w*32 + s*16 + col
  float wih_r[4][2], bias_r[4][2];
#pragma unroll
  for (int g = 0; g < 4; ++g)
#pragma unroll
    for (int s = 0; s < 2; ++s) {
      int j = g * 128 + w * 32 + s * 16 + col;
      wih_r[g][s] = Wih[j];
      bias_r[g][s] = bih[j] + bhh[j];
    }
  float wout_r[2];
  wout_r[0] = Wout[w * 32 + col];
  wout_r[1] = Wout[w * 32 + 16 + col];
  const float bout = boutp[0];

  float c_r[2][2][4];  // [mt][s][reg] cell state, fp32, in registers
#pragma unroll
  for (int mt = 0; mt < 2; ++mt)
#pragma unroll
    for (int s = 0; s < 2; ++s)
#pragma unroll
      for (int r = 0; r < 4; ++r) c_r[mt][s][r] = 0.f;

  float hn0[2][4];  // s=0 h_new held until s=1 pairs it for staging
  float pp[2][4];   // pred partial

  __syncthreads();  // prologue: buf0 + xs[0] ready

#pragma unroll 1
  for (int t = 0; t < SEQ; ++t) {
    const int cur = t & 1, nxt = cur ^ 1;

    // drain pred of t-1 (predp[(t-1)&1] == predp[nxt] complete as of last
    // barrier; this iteration's epilogue writes predp[cur], no clash)
    if (t > 0 && tid < BT) {
      float p = predp[nxt][0][tid] + predp[nxt][1][tid] +
                predp[nxt][2][tid] + predp[nxt][3][tid] + bout;
      out[(size_t)(rowbase + tid) * 7 + (t - 1)] = p;
    }
    // prefetch input for t+1 into the other xs buffer (consumed after the
    // end-of-body barrier; old contents were last read before prev barrier)
    if (t + 1 < SEQ && tid < BT) {
      xs[nxt][tid] = x[(size_t)(rowbase + tid) * 7 + t];
    }

#pragma unroll
    for (int s = 0; s < 2; ++s) {
      floatx4 acc[2][4];  // [mt][g]
#pragma unroll
      for (int mt = 0; mt < 2; ++mt)
#pragma unroll
        for (int g = 0; g < 4; ++g)
          acc[mt][g] = (floatx4){0.f, 0.f, 0.f, 0.f};

#pragma unroll
      for (int kk = 0; kk < 4; ++kk) {
        half8 ahi[2], alo[2];
        const int k0 = kk * 32 + quad * 8;
#pragma unroll
        for (int mt = 0; mt < 2; ++mt) {
          const int row = mt * 16 + col;  // A: m = lane&15 within tile
          ahi[mt] = *(const half8*)&Ahi[cur][row][k0];
          alo[mt] = *(const half8*)&Alo[cur][row][k0];
        }
#pragma unroll
        for (int g = 0; g < 4; ++g) {
          const int nt = g * 8 + w * 2 + s;
          const int off = ((nt * 4 + kk) * 64 + lane) * 8;
          half8 bhi = *(const half8*)(Bp + off);
#pragma unroll
          for (int mt = 0; mt < 2; ++mt) {
            acc[mt][g] = mfma16(ahi[mt], bhi, acc[mt][g]);  // hi*hi
            acc[mt][g] = mfma16(alo[mt], bhi, acc[mt][g]);  // lo*hi
          }
        }
      }

#pragma unroll
      for (int mt = 0; mt < 2; ++mt) {
#pragma unroll
        for (int r = 0; r < 4; ++r) {
          const int b_loc = mt * 16 + quad * 4 + r;  // C row
          const float xv = xs[cur][b_loc];
          float G0 = acc[mt][0][r] + (xv * wih_r[0][s] + bias_r[0][s]);
          float G1 = acc[mt][1][r] + (xv * wih_r[1][s] + bias_r[1][s]);
          float G2 = acc[mt][2][r] + (xv * wih_r[2][s] + bias_r[2][s]);
          float G3 = acc[mt][3][r] + (xv * wih_r[3][s] + bias_r[3][s]);
          float ig = fsig(G0);
          float fg = fsig(G1);
          float gg = ftanh(G2);
          float og = fsig(G3);
          float cn = fg * c_r[mt][s][r] + ig * gg;
          c_r[mt][s][r] = cn;
          float hn = og * ftanh(cn);
          if (s == 0) {
            hn0[mt][r] = hn;
            pp[mt][r] = hn * wout_r[0];
          } else {
            pp[mt][r] += hn * wout_r[1];
            // stage h_new (hi/lo fp16) into the NEXT buffer
            float h0 = hn0[mt][r];
            _Float16 h0h = (_Float16)h0;
            _Float16 h0l = (_Float16)(h0 - (float)h0h);
            _Float16 h1h = (_Float16)hn;
            _Float16 h1l = (_Float16)(hn - (float)h1h);
            const int hc0 = w * 32 + col;
            Ahi[nxt][b_loc][hc0] = h0h;
            Alo[nxt][b_loc][hc0] = h0l;
            Ahi[nxt][b_loc][hc0 + 16] = h1h;
            Alo[nxt][b_loc][hc0 + 16] = h1l;
            // reduce pred over the 16 cols this wave holds for this row
            float v = pp[mt][r];
            v += __shfl_xor(v, 1, 64);
            v += __shfl_xor(v, 2, 64);
            v += __shfl_xor(v, 4, 64);
            v += __shfl_xor(v, 8, 64);
            if (col == 0) predp[cur][w][b_loc] = v;
          }
        }
      }
    }
    __syncthreads();  // single barrier: staging, predp, xs prefetch complete
  }

  // drain pred of t=6 (predp[(SEQ-1)&1] = predp[0])
  if (tid < BT) {
    float p = predp[0][0][tid] + predp[0][1][tid] +
              predp[0][2][tid] + predp[0][3][tid] + bout;
    out[(size_t)(rowbase + tid) * 7 + (SEQ - 1)] = p;
  }
}

extern "C" void kernel_launch(void* const* d_in, const int* in_sizes, int n_in,
                              void* d_out, int out_size, void* d_ws, size_t ws_size,
                              hipStream_t stream) {
  const float* x    = (const float*)d_in[0];
  const float* x0   = (const float*)d_in[1];
  const float* Wih  = (const float*)d_in[2];
  const float* Whh  = (const float*)d_in[3];
  const float* bih  = (const float*)d_in[4];
  const float* bhh  = (const float*)d_in[5];
  const float* Wout = (const float*)d_in[6];
  const float* bout = (const float*)d_in[7];
  float* out = (float*)d_out;
  _Float16* Bp = (_Float16*)d_ws;  // 128 KB fragment-major W_hh (fp16 hi)

  pack_kernel<<<256, 256, 0, stream>>>(Whh, Bp);
  lstm_kernel<<<65536 / BT, 256, 0, stream>>>(x, x0, Wih, bih, bhh, Wout, bout,
                                              Bp, out);
}

// Round 6
// 202.810 us; speedup vs baseline: 1.9941x; 1.1730x over previous
//
#include <hip/hip_runtime.h>

// LSTM: HIDDEN=128, SEQ=7, BATCH=65536. fp32 in/out.
// fp16 MFMA GEMM per timestep, c state in registers, h staged via LDS,
// double-buffered, 1 barrier/timestep.
//
// R2: launch_bounds fix — spills gone. 544->297us.
// R3: dropped W_lo pass (absmax unchanged 2.44e-4). 297->252us.
// R4: BT=32 + dbuf LDS + 1 barrier/t; (256,3) -> 84 VGPR spills. REGRESSION.
// R5: (256,2): 200us. VALUBusy 51%, MFMA cycle-busy ~7% -> epilogue-bound.
// R6: drop the A-lo pass too (pure fp16 h). absmax floor appears to be
//     harness-side (identical 2.44e-4 for 3- and 2-pass); predicted
//     GEMM-rounding contribution ~2e-4 worst-case, under 1.43e-3 threshold.
//     Halves MFMA + A-reads + staging; LDS 36->18.5KB -> 4 blocks/CU.

#define SEQ 7
#define BT 32

typedef _Float16 half8 __attribute__((ext_vector_type(8)));
typedef float floatx4 __attribute__((ext_vector_type(4)));

__device__ __forceinline__ floatx4 mfma16(half8 a, half8 b, floatx4 c) {
  return __builtin_amdgcn_mfma_f32_16x16x32_f16(a, b, c, 0, 0, 0);
}

__device__ __forceinline__ float fsig(float v) {
  float e = __expf(-v);
  return __builtin_amdgcn_rcpf(1.0f + e);
}
__device__ __forceinline__ float ftanh(float v) {
  float e = __expf(-2.0f * v);
  return 2.0f * __builtin_amdgcn_rcpf(1.0f + e) - 1.0f;
}

// Pack W_hh [512][128] fp32 into fragment-major fp16 (hi part only).
// B-operand layout for mfma_f32_16x16x32_f16: lane = kq*16 + col holds
// B[k = kq*8 + jj][n = col] for the 16-col tile.
__global__ void pack_kernel(const float* __restrict__ Whh,
                            _Float16* __restrict__ Bp) {
  int idx = blockIdx.x * 256 + threadIdx.x;   // 0..65535 = j*128 + k
  float wv = Whh[idx];
  _Float16 hi = (_Float16)wv;
  int j = idx >> 7, k = idx & 127;
  int nt = j >> 4, col = j & 15;              // 16-col N-tile, col within
  int kk = k >> 5, r = k & 31;                // 32-K step, k within
  int kq = r >> 3, jj = r & 7;
  int base = (((nt << 2) + kk) * 64 + (kq << 4) + col) * 8 + jj;
  Bp[base] = hi;
}

__launch_bounds__(256, 2)
__global__ void lstm_kernel(const float* __restrict__ x,
                            const float* __restrict__ x0,
                            const float* __restrict__ Wih,
                            const float* __restrict__ bih,
                            const float* __restrict__ bhh,
                            const float* __restrict__ Wout,
                            const float* __restrict__ boutp,
                            const _Float16* __restrict__ Bp,
                            float* __restrict__ out) {
  // h staged as fp16, double-buffered: [buf][row][k] with +8 pad
  // (272B stride -> conflict-free ds_read_b128 A-fragments, 16B aligned).
  __shared__ _Float16 Ah[2][BT][136];
  __shared__ float xs[2][BT];
  __shared__ float predp[2][4][BT];

  const int tid = threadIdx.x;
  const int w = tid >> 6;          // wave 0..3: owns hc [32w, 32w+32)
  const int lane = tid & 63;
  const int col = lane & 15;
  const int quad = lane >> 4;
  const int rowbase = blockIdx.x * BT;

  // zero h state buf0 (h0 = 0)
  {
    unsigned int* a0 = (unsigned int*)&Ah[0][0][0];
    for (int i = tid; i < BT * 136 / 2; i += 256) a0[i] = 0u;
  }
  if (tid < BT) xs[0][tid] = x0[rowbase + tid];  // input for t=0

  // per-lane constants: gate col j = g*128 + w*32 + s*16 + col
  float wih_r[4][2], bias_r[4][2];
#pragma unroll
  for (int g = 0; g < 4; ++g)
#pragma unroll
    for (int s = 0; s < 2; ++s) {
      int j = g * 128 + w * 32 + s * 16 + col;
      wih_r[g][s] = Wih[j];
      bias_r[g][s] = bih[j] + bhh[j];
    }
  float wout_r[2];
  wout_r[0] = Wout[w * 32 + col];
  wout_r[1] = Wout[w * 32 + 16 + col];
  const float bout = boutp[0];

  float c_r[2][2][4];  // [mt][s][reg] cell state, fp32, in registers
#pragma unroll
  for (int mt = 0; mt < 2; ++mt)
#pragma unroll
    for (int s = 0; s < 2; ++s)
#pragma unroll
      for (int r = 0; r < 4; ++r) c_r[mt][s][r] = 0.f;

  float hn0[2][4];  // s=0 h_new held until s=1 pairs it for staging
  float pp[2][4];   // pred partial

  __syncthreads();  // prologue: buf0 + xs[0] ready

#pragma unroll 1
  for (int t = 0; t < SEQ; ++t) {
    const int cur = t & 1, nxt = cur ^ 1;

    // drain pred of t-1 (predp[nxt] complete as of last barrier)
    if (t > 0 && tid < BT) {
      float p = predp[nxt][0][tid] + predp[nxt][1][tid] +
                predp[nxt][2][tid] + predp[nxt][3][tid] + bout;
      out[(size_t)(rowbase + tid) * 7 + (t - 1)] = p;
    }
    // prefetch input for t+1 into the other xs buffer
    if (t + 1 < SEQ && tid < BT) {
      xs[nxt][tid] = x[(size_t)(rowbase + tid) * 7 + t];
    }

#pragma unroll
    for (int s = 0; s < 2; ++s) {
      floatx4 acc[2][4];  // [mt][g]
#pragma unroll
      for (int mt = 0; mt < 2; ++mt)
#pragma unroll
        for (int g = 0; g < 4; ++g)
          acc[mt][g] = (floatx4){0.f, 0.f, 0.f, 0.f};

#pragma unroll
      for (int kk = 0; kk < 4; ++kk) {
        half8 ah[2];
        const int k0 = kk * 32 + quad * 8;
#pragma unroll
        for (int mt = 0; mt < 2; ++mt) {
          const int row = mt * 16 + col;  // A: m = lane&15 within tile
          ah[mt] = *(const half8*)&Ah[cur][row][k0];
        }
#pragma unroll
        for (int g = 0; g < 4; ++g) {
          const int nt = g * 8 + w * 2 + s;
          const int off = ((nt * 4 + kk) * 64 + lane) * 8;
          half8 bhi = *(const half8*)(Bp + off);
#pragma unroll
          for (int mt = 0; mt < 2; ++mt)
            acc[mt][g] = mfma16(ah[mt], bhi, acc[mt][g]);
        }
      }

#pragma unroll
      for (int mt = 0; mt < 2; ++mt) {
#pragma unroll
        for (int r = 0; r < 4; ++r) {
          const int b_loc = mt * 16 + quad * 4 + r;  // C row
          const float xv = xs[cur][b_loc];
          float G0 = acc[mt][0][r] + (xv * wih_r[0][s] + bias_r[0][s]);
          float G1 = acc[mt][1][r] + (xv * wih_r[1][s] + bias_r[1][s]);
          float G2 = acc[mt][2][r] + (xv * wih_r[2][s] + bias_r[2][s]);
          float G3 = acc[mt][3][r] + (xv * wih_r[3][s] + bias_r[3][s]);
          float ig = fsig(G0);
          float fg = fsig(G1);
          float gg = ftanh(G2);
          float og = fsig(G3);
          float cn = fg * c_r[mt][s][r] + ig * gg;
          c_r[mt][s][r] = cn;
          float hn = og * ftanh(cn);
          if (s == 0) {
            hn0[mt][r] = hn;
            pp[mt][r] = hn * wout_r[0];
          } else {
            pp[mt][r] += hn * wout_r[1];
            // stage h_new (fp16) into the NEXT buffer
            const int hc0 = w * 32 + col;
            Ah[nxt][b_loc][hc0] = (_Float16)hn0[mt][r];
            Ah[nxt][b_loc][hc0 + 16] = (_Float16)hn;
            // reduce pred over the 16 cols this wave holds for this row
            float v = pp[mt][r];
            v += __shfl_xor(v, 1, 64);
            v += __shfl_xor(v, 2, 64);
            v += __shfl_xor(v, 4, 64);
            v += __shfl_xor(v, 8, 64);
            if (col == 0) predp[cur][w][b_loc] = v;
          }
        }
      }
    }
    __syncthreads();  // single barrier: staging, predp, xs prefetch complete
  }

  // drain pred of t=6 (predp[(SEQ-1)&1] = predp[0])
  if (tid < BT) {
    float p = predp[0][0][tid] + predp[0][1][tid] +
              predp[0][2][tid] + predp[0][3][tid] + bout;
    out[(size_t)(rowbase + tid) * 7 + (SEQ - 1)] = p;
  }
}

extern "C" void kernel_launch(void* const* d_in, const int* in_sizes, int n_in,
                              void* d_out, int out_size, void* d_ws, size_t ws_size,
                              hipStream_t stream) {
  const float* x    = (const float*)d_in[0];
  const float* x0   = (const float*)d_in[1];
  const float* Wih  = (const float*)d_in[2];
  const float* Whh  = (const float*)d_in[3];
  const float* bih  = (const float*)d_in[4];
  const float* bhh  = (const float*)d_in[5];
  const float* Wout = (const float*)d_in[6];
  const float* bout = (const float*)d_in[7];
  float* out = (float*)d_out;
  _Float16* Bp = (_Float16*)d_ws;  // 128 KB fragment-major W_hh (fp16 hi)

  pack_kernel<<<256, 256, 0, stream>>>(Whh, Bp);
  lstm_kernel<<<65536 / BT, 256, 0, stream>>>(x, x0, Wih, bih, bhh, Wout, bout,
                                              Bp, out);
}

// Round 7
// 196.288 us; speedup vs baseline: 2.0604x; 1.0332x over previous
//
#include <hip/hip_runtime.h>

// LSTM: HIDDEN=128, SEQ=7, BATCH=65536. fp32 in/out.
// fp16 MFMA GEMM per timestep, c state in registers, h staged via LDS,
// double-buffered, 1 barrier/timestep.
//
// R2: launch_bounds fix — spills gone. 544->297us.
// R3: dropped W_lo pass (absmax unchanged 2.44e-4). 297->252us.
// R4: BT=32 + dbuf + (256,3) -> 84 VGPR spills. REGRESSION (368us).
// R5: (256,2): 200us. VALU-bound.
// R6: pure-fp16 h (absmax STILL 2.44e-4 = harness bf16 floor). 153us.
//     Trans-pipe model: 10 trans/element = ~30us floor; epilogue-bound.
// R7: fused-reciprocal cell math: one rcp for (i,f,g,c-update), one for
//     (o, tanh(c)). 10 -> 7 trans/element.
//     c' = [c(1+A)(1+C) + (1-C)(1+B)] / [(1+A)(1+B)(1+C)],
//     h  = (1-E) / [(1+D)(1+E)], A=e^-Gi, B=e^-Gf, C=e^-2Gg, D=e^-Go,
//     E=e^-2c'. Max intermediate ~7e20, fp32-safe; err ~5ulp.

#define SEQ 7
#define BT 32

typedef _Float16 half8 __attribute__((ext_vector_type(8)));
typedef float floatx4 __attribute__((ext_vector_type(4)));

__device__ __forceinline__ floatx4 mfma16(half8 a, half8 b, floatx4 c) {
  return __builtin_amdgcn_mfma_f32_16x16x32_f16(a, b, c, 0, 0, 0);
}

// Pack W_hh [512][128] fp32 into fragment-major fp16 (hi part only).
// B-operand layout for mfma_f32_16x16x32_f16: lane = kq*16 + col holds
// B[k = kq*8 + jj][n = col] for the 16-col tile.
__global__ void pack_kernel(const float* __restrict__ Whh,
                            _Float16* __restrict__ Bp) {
  int idx = blockIdx.x * 256 + threadIdx.x;   // 0..65535 = j*128 + k
  float wv = Whh[idx];
  _Float16 hi = (_Float16)wv;
  int j = idx >> 7, k = idx & 127;
  int nt = j >> 4, col = j & 15;              // 16-col N-tile, col within
  int kk = k >> 5, r = k & 31;                // 32-K step, k within
  int kq = r >> 3, jj = r & 7;
  int base = (((nt << 2) + kk) * 64 + (kq << 4) + col) * 8 + jj;
  Bp[base] = hi;
}

__launch_bounds__(256, 2)
__global__ void lstm_kernel(const float* __restrict__ x,
                            const float* __restrict__ x0,
                            const float* __restrict__ Wih,
                            const float* __restrict__ bih,
                            const float* __restrict__ bhh,
                            const float* __restrict__ Wout,
                            const float* __restrict__ boutp,
                            const _Float16* __restrict__ Bp,
                            float* __restrict__ out) {
  // h staged as fp16, double-buffered: [buf][row][k] with +8 pad
  // (272B stride -> conflict-free ds_read_b128 A-fragments, 16B aligned).
  __shared__ _Float16 Ah[2][BT][136];
  __shared__ float xs[2][BT];
  __shared__ float predp[2][4][BT];

  const int tid = threadIdx.x;
  const int w = tid >> 6;          // wave 0..3: owns hc [32w, 32w+32)
  const int lane = tid & 63;
  const int col = lane & 15;
  const int quad = lane >> 4;
  const int rowbase = blockIdx.x * BT;

  // zero h state buf0 (h0 = 0)
  {
    unsigned int* a0 = (unsigned int*)&Ah[0][0][0];
    for (int i = tid; i < BT * 136 / 2; i += 256) a0[i] = 0u;
  }
  if (tid < BT) xs[0][tid] = x0[rowbase + tid];  // input for t=0

  // per-lane constants: gate col j = g*128 + w*32 + s*16 + col
  float wih_r[4][2], bias_r[4][2];
#pragma unroll
  for (int g = 0; g < 4; ++g)
#pragma unroll
    for (int s = 0; s < 2; ++s) {
      int j = g * 128 + w * 32 + s * 16 + col;
      wih_r[g][s] = Wih[j];
      bias_r[g][s] = bih[j] + bhh[j];
    }
  float wout_r[2];
  wout_r[0] = Wout[w * 32 + col];
  wout_r[1] = Wout[w * 32 + 16 + col];
  const float bout = boutp[0];

  float c_r[2][2][4];  // [mt][s][reg] cell state, fp32, in registers
#pragma unroll
  for (int mt = 0; mt < 2; ++mt)
#pragma unroll
    for (int s = 0; s < 2; ++s)
#pragma unroll
      for (int r = 0; r < 4; ++r) c_r[mt][s][r] = 0.f;

  float hn0[2][4];  // s=0 h_new held until s=1 pairs it for staging
  float pp[2][4];   // pred partial

  __syncthreads();  // prologue: buf0 + xs[0] ready

#pragma unroll 1
  for (int t = 0; t < SEQ; ++t) {
    const int cur = t & 1, nxt = cur ^ 1;

    // drain pred of t-1 (predp[nxt] complete as of last barrier)
    if (t > 0 && tid < BT) {
      float p = predp[nxt][0][tid] + predp[nxt][1][tid] +
                predp[nxt][2][tid] + predp[nxt][3][tid] + bout;
      out[(size_t)(rowbase + tid) * 7 + (t - 1)] = p;
    }
    // prefetch input for t+1 into the other xs buffer
    if (t + 1 < SEQ && tid < BT) {
      xs[nxt][tid] = x[(size_t)(rowbase + tid) * 7 + t];
    }

#pragma unroll
    for (int s = 0; s < 2; ++s) {
      floatx4 acc[2][4];  // [mt][g]
#pragma unroll
      for (int mt = 0; mt < 2; ++mt)
#pragma unroll
        for (int g = 0; g < 4; ++g)
          acc[mt][g] = (floatx4){0.f, 0.f, 0.f, 0.f};

#pragma unroll
      for (int kk = 0; kk < 4; ++kk) {
        half8 ah[2];
        const int k0 = kk * 32 + quad * 8;
#pragma unroll
        for (int mt = 0; mt < 2; ++mt) {
          const int row = mt * 16 + col;  // A: m = lane&15 within tile
          ah[mt] = *(const half8*)&Ah[cur][row][k0];
        }
#pragma unroll
        for (int g = 0; g < 4; ++g) {
          const int nt = g * 8 + w * 2 + s;
          const int off = ((nt * 4 + kk) * 64 + lane) * 8;
          half8 bhi = *(const half8*)(Bp + off);
#pragma unroll
          for (int mt = 0; mt < 2; ++mt)
            acc[mt][g] = mfma16(ah[mt], bhi, acc[mt][g]);
        }
      }

#pragma unroll
      for (int mt = 0; mt < 2; ++mt) {
#pragma unroll
        for (int r = 0; r < 4; ++r) {
          const int b_loc = mt * 16 + quad * 4 + r;  // C row
          const float xv = xs[cur][b_loc];
          float Gi = acc[mt][0][r] + (xv * wih_r[0][s] + bias_r[0][s]);
          float Gf = acc[mt][1][r] + (xv * wih_r[1][s] + bias_r[1][s]);
          float Gg = acc[mt][2][r] + (xv * wih_r[2][s] + bias_r[2][s]);
          float Go = acc[mt][3][r] + (xv * wih_r[3][s] + bias_r[3][s]);
          // fused-reciprocal cell update (7 trans vs 10):
          // i*g + f*c = [c(1+A)(1+C) + (1-C)(1+B)] / [(1+A)(1+B)(1+C)]
          float A = __expf(-Gi);
          float B = __expf(-Gf);
          float C = __expf(-2.0f * Gg);
          float a1 = 1.0f + A, b1 = 0.0f + 1.0f + B, c1 = 1.0f + C;
          float ac = a1 * c1;
          float num = c_r[mt][s][r] * ac + (1.0f - C) * b1;
          float cn = num * __builtin_amdgcn_rcpf(ac * b1);
          c_r[mt][s][r] = cn;
          // h = o * tanh(cn) = (1-E) / [(1+D)(1+E)]
          float D = __expf(-Go);
          float E = __expf(-2.0f * cn);
          float hn = (1.0f - E) *
                     __builtin_amdgcn_rcpf((1.0f + D) * (1.0f + E));
          if (s == 0) {
            hn0[mt][r] = hn;
            pp[mt][r] = hn * wout_r[0];
          } else {
            pp[mt][r] += hn * wout_r[1];
            // stage h_new (fp16) into the NEXT buffer
            const int hc0 = w * 32 + col;
            Ah[nxt][b_loc][hc0] = (_Float16)hn0[mt][r];
            Ah[nxt][b_loc][hc0 + 16] = (_Float16)hn;
            // reduce pred over the 16 cols this wave holds for this row
            float v = pp[mt][r];
            v += __shfl_xor(v, 1, 64);
            v += __shfl_xor(v, 2, 64);
            v += __shfl_xor(v, 4, 64);
            v += __shfl_xor(v, 8, 64);
            if (col == 0) predp[cur][w][b_loc] = v;
          }
        }
      }
    }
    __syncthreads();  // single barrier: staging, predp, xs prefetch complete
  }

  // drain pred of t=6 (predp[(SEQ-1)&1] = predp[0])
  if (tid < BT) {
    float p = predp[0][0][tid] + predp[0][1][tid] +
              predp[0][2][tid] + predp[0][3][tid] + bout;
    out[(size_t)(rowbase + tid) * 7 + (SEQ - 1)] = p;
  }
}

extern "C" void kernel_launch(void* const* d_in, const int* in_sizes, int n_in,
                              void* d_out, int out_size, void* d_ws, size_t ws_size,
                              hipStream_t stream) {
  const float* x    = (const float*)d_in[0];
  const float* x0   = (const float*)d_in[1];
  const float* Wih  = (const float*)d_in[2];
  const float* Whh  = (const float*)d_in[3];
  const float* bih  = (const float*)d_in[4];
  const float* bhh  = (const float*)d_in[5];
  const float* Wout = (const float*)d_in[6];
  const float* bout = (const float*)d_in[7];
  float* out = (float*)d_out;
  _Float16* Bp = (_Float16*)d_ws;  // 128 KB fragment-major W_hh (fp16 hi)

  pack_kernel<<<256, 256, 0, stream>>>(Whh, Bp);
  lstm_kernel<<<65536 / BT, 256, 0, stream>>>(x, x0, Wih, bih, bhh, Wout, bout,
                                              Bp, out);
}